// Round 5
// baseline (134.147 us; speedup 1.0000x reference)
//
#include <hip/hip_runtime.h>

typedef __bf16 bf16;
typedef __bf16 bf16x8 __attribute__((ext_vector_type(8)));
typedef float f32x4 __attribute__((ext_vector_type(4)));

__device__ __forceinline__ f32x4 mfma16(bf16x8 a, bf16x8 b, f32x4 c) {
  return __builtin_amdgcn_mfma_f32_16x16x32_bf16(a, b, c, 0, 0, 0);
}

// async global->LDS 16B; LDS dest is wave-uniform base, lane l writes base+l*16.
__device__ __forceinline__ void gload16(const void* g, void* l) {
  __builtin_amdgcn_global_load_lds(
      (const __attribute__((address_space(1))) void*)g,
      (__attribute__((address_space(3))) void*)(uint32_t)(size_t)l, 16, 0, 0);
}

#define SB0 __builtin_amdgcn_sched_barrier(0)

template <int N> __device__ __forceinline__ void waitv() {
  if constexpr (N == 16) asm volatile("s_waitcnt vmcnt(16)" ::: "memory");
  else if constexpr (N == 8) asm volatile("s_waitcnt vmcnt(8)" ::: "memory");
  else asm volatile("s_waitcnt vmcnt(0)" ::: "memory");
}

__device__ __forceinline__ bf16x8 cvt8(float4 a, float4 b) {
  bf16x8 r;
  r[0] = (bf16)a.x; r[1] = (bf16)a.y; r[2] = (bf16)a.z; r[3] = (bf16)a.w;
  r[4] = (bf16)b.x; r[5] = (bf16)b.y; r[6] = (bf16)b.z; r[7] = (bf16)b.w;
  return r;
}

// ---------------- gating ----------------
__global__ __launch_bounds__(256) void gating_kernel(
    const float* __restrict__ x, const float* __restrict__ gw,
    const float* __restrict__ gb, bf16* __restrict__ xgb,
    float* __restrict__ gbuf) {
  const int b = blockIdx.x, tid = threadIdx.x;
  __shared__ float xs[256];
  __shared__ float gs[8];
  xs[tid] = x[b * 256 + tid];
  __syncthreads();
  if (tid < 8) {
    float acc = gb[tid];
    for (int i = 0; i < 256; ++i) acc += xs[i] * gw[i * 8 + tid];
    gs[tid] = acc;
  }
  __syncthreads();
  if (tid == 0) {
    float m = gs[0];
    for (int l = 1; l < 8; ++l) m = fmaxf(m, gs[l]);
    float s = 0.f, e[8];
    for (int l = 0; l < 8; ++l) { e[l] = expf(gs[l] - m); s += e[l]; }
    float inv = 1.f / s;
    for (int l = 0; l < 8; ++l) gs[l] = e[l] * inv;
  }
  __syncthreads();
  if (tid < 8) gbuf[b * 8 + tid] = gs[tid];
  bf16* dst = xgb + (size_t)b * 2048;
  for (int k = tid; k < 2048; k += 256)
    dst[k] = (bf16)(xs[k >> 3] * gs[k & 7]);
}

// ---------------- merged weight transform ----------------
template <int CIN, int COUT, int COUTP>
__device__ __forceinline__ void cw_one(const float* __restrict__ w,
                                       bf16* __restrict__ wp, int idx) {
  constexpr int K = 4 * CIN;
  int ic = idx & (CIN - 1);
  int t = (idx / CIN) & 3;
  int oc = (idx / K) % COUTP;
  int p = idx / (K * COUTP);
  bf16 v = (bf16)0.f;
  if (oc < COUT) {
    int py = p >> 1, px = p & 1, tyi = t >> 1, txi = t & 1;
    int ky = py == 0 ? (tyi ? 3 : 1) : (tyi ? 2 : 0);
    int kx = px == 0 ? (txi ? 3 : 1) : (txi ? 2 : 0);
    v = (bf16)w[((ic * COUT + oc) * 4 + ky) * 4 + kx];
  }
  wp[idx] = v;
}

__global__ __launch_bounds__(256) void convert_w_all(
    const float* __restrict__ w1, bf16* __restrict__ w1p,
    const float* __restrict__ w2, bf16* __restrict__ w2p,
    const float* __restrict__ w3, bf16* __restrict__ w3p) {
  int idx = blockIdx.x * 256 + threadIdx.x;
  if (idx < 131072) cw_one<128, 64, 64>(w1, w1p, idx);
  else if (idx < 163840) cw_one<64, 32, 32>(w2, w2p, idx - 131072);
  else if (idx < 172032) cw_one<32, 3, 16>(w3, w3p, idx - 163840);
}

// ---------------- merged halo zero ----------------
template <int HP, int WP, int C>
__device__ __forceinline__ void bz_one(bf16* __restrict__ buf, int idx) {
  constexpr int NCELL = 2 * WP + 2 * (HP - 2);
  constexpr int C8 = C / 8;
  int c8 = idx % C8;
  int rem = idx / C8;
  int cell = rem % NCELL;
  int b = rem / NCELL;
  int y, x;
  if (cell < WP) { y = 0; x = cell; }
  else if (cell < 2 * WP) { y = HP - 1; x = cell - WP; }
  else { int r2 = cell - 2 * WP; y = 1 + (r2 >> 1); x = (r2 & 1) ? WP - 1 : 0; }
  bf16x8 z = {};
  *(bf16x8*)(buf + ((size_t)(b * HP + y) * WP + x) * C + c8 * 8) = z;
}

__global__ __launch_bounds__(256) void border_zero_all(
    bf16* __restrict__ h0t, bf16* __restrict__ h1, bf16* __restrict__ h2) {
  int idx = blockIdx.x * 256 + threadIdx.x;
  if (idx < 147456) bz_one<10, 10, 128>(h0t, idx);
  else if (idx < 286720) bz_one<18, 18, 64>(h1, idx - 147456);
  else if (idx < 421888) bz_one<34, 34, 32>(h2, idx - 286720);
}

// ---------------- fused ME GEMM, counted-vmcnt pipeline ----------------
// C[o,b] = bf16(pw[o,:]) . xgb[b,:] + dot(g[b],pb[o]). 256 blocks x 32 M-rows, N=256.
// B: 4 LDS bufs x 32KB, staged 3-deep via swizzled-source gload16. A: f32 direct,
// 3-deep register queue. Raw s_barrier + s_waitcnt vmcnt(16) (never 0 in loop).
__global__ __launch_bounds__(512) void me_gemm_kernel(
    const float* __restrict__ pw, const bf16* __restrict__ xgb,
    const float* __restrict__ pb, const float* __restrict__ gbuf,
    bf16* __restrict__ h0t) {
  __shared__ char sB[131072];  // 4 x 32KB
  const int tid = threadIdx.x, wv = tid >> 6, l = tid & 63;
  const int lr = l & 15, lkg = l >> 4;
  const int wm = wv & 1, wn = wv >> 1;
  const int oM0 = blockIdx.x * 32;

  // B staging: chunk ch = i*512+tid -> row r=ch>>3, 16B slot c=ch&7 (inverse-swizzled src)
  const bf16* bsrc[4];
  int bdst[4];
#pragma unroll
  for (int i = 0; i < 4; ++i) {
    int ch = i * 512 + tid;
    int r = ch >> 3, c = ch & 7;
    int sb = (c * 16) ^ ((r & 7) << 4);
    bsrc[i] = xgb + (size_t)r * 2048 + (sb >> 1);
    bdst[i] = (i * 512 + wv * 64) * 16;
  }
  const float* pAf = pw + (size_t)(oM0 + wm * 16 + lr) * 2048 + lkg * 8;

  int raddrB[4][2];
#pragma unroll
  for (int n = 0; n < 4; ++n) {
    int rb = wn * 64 + n * 16 + lr;
#pragma unroll
    for (int ks = 0; ks < 2; ++ks)
      raddrB[n][ks] = rb * 128 + ((ks * 64 + lkg * 16) ^ ((rb & 7) << 4));
  }

  float4 aq[3][4];   // only constant-indexed (macro S)
  f32x4 acc[4] = {};

#define STAGE_B(KT) { const int _bo = ((KT) & 3) * 32768; const int _ke = (KT) * 64; \
    gload16(bsrc[0] + _ke, sB + _bo + bdst[0]); \
    gload16(bsrc[1] + _ke, sB + _bo + bdst[1]); \
    gload16(bsrc[2] + _ke, sB + _bo + bdst[2]); \
    gload16(bsrc[3] + _ke, sB + _bo + bdst[3]); } SB0;
#define LOAD_A(KT, S) { const float* _p = pAf + (KT) * 64; \
    aq[S][0] = *(const float4*)(_p);      aq[S][1] = *(const float4*)(_p + 4); \
    aq[S][2] = *(const float4*)(_p + 32); aq[S][3] = *(const float4*)(_p + 36); } SB0;
#define COMPUTE(KT, AF0, AF1) { const char* _b = sB + ((KT) & 3) * 32768; \
    bf16x8 bv; \
    bv = *(const bf16x8*)(_b + raddrB[0][0]); acc[0] = mfma16(AF0, bv, acc[0]); \
    bv = *(const bf16x8*)(_b + raddrB[1][0]); acc[1] = mfma16(AF0, bv, acc[1]); \
    bv = *(const bf16x8*)(_b + raddrB[2][0]); acc[2] = mfma16(AF0, bv, acc[2]); \
    bv = *(const bf16x8*)(_b + raddrB[3][0]); acc[3] = mfma16(AF0, bv, acc[3]); \
    bv = *(const bf16x8*)(_b + raddrB[0][1]); acc[0] = mfma16(AF1, bv, acc[0]); \
    bv = *(const bf16x8*)(_b + raddrB[1][1]); acc[1] = mfma16(AF1, bv, acc[1]); \
    bv = *(const bf16x8*)(_b + raddrB[2][1]); acc[2] = mfma16(AF1, bv, acc[2]); \
    bv = *(const bf16x8*)(_b + raddrB[3][1]); acc[3] = mfma16(AF1, bv, acc[3]); }
#define ITER_I(KT, S) { waitv<16>(); SB0; __builtin_amdgcn_s_barrier(); SB0; \
    bf16x8 _af0 = cvt8(aq[S][0], aq[S][1]); bf16x8 _af1 = cvt8(aq[S][2], aq[S][3]); \
    STAGE_B((KT) + 3); LOAD_A((KT) + 3, S); COMPUTE(KT, _af0, _af1); }
#define ITER_N(KT, S, WN) { waitv<WN>(); SB0; __builtin_amdgcn_s_barrier(); SB0; \
    bf16x8 _af0 = cvt8(aq[S][0], aq[S][1]); bf16x8 _af1 = cvt8(aq[S][2], aq[S][3]); \
    COMPUTE(KT, _af0, _af1); }

  // prologue: B0,A0,B1,A1,B2,A2 = 24 outstanding
  STAGE_B(0); LOAD_A(0, 0);
  STAGE_B(1); LOAD_A(1, 1);
  STAGE_B(2); LOAD_A(2, 2);

  for (int kt = 0; kt < 27; kt += 3) {
    ITER_I(kt + 0, 0);
    ITER_I(kt + 1, 1);
    ITER_I(kt + 2, 2);
  }
  ITER_I(27, 0);
  ITER_I(28, 1);
  ITER_N(29, 2, 16);
  ITER_N(30, 0, 8);
  ITER_N(31, 1, 0);

  // epilogue: + dot(g[b], pb[o]) -> h0t padded channels-last
  float4 g0[4], g1[4];
#pragma unroll
  for (int n = 0; n < 4; ++n) {
    int b = wn * 64 + n * 16 + lr;
    g0[n] = *(const float4*)(gbuf + b * 8);
    g1[n] = *(const float4*)(gbuf + b * 8 + 4);
  }
#pragma unroll
  for (int r = 0; r < 4; ++r) {
    int o = oM0 + wm * 16 + lkg * 4 + r;
    float4 p0 = *(const float4*)(pb + o * 8);
    float4 p1 = *(const float4*)(pb + o * 8 + 4);
    int cch = o >> 6, y = (o >> 3) & 7, xx = o & 7;
#pragma unroll
    for (int n = 0; n < 4; ++n) {
      int b = wn * 64 + n * 16 + lr;
      float bias = g0[n].x * p0.x + g0[n].y * p0.y + g0[n].z * p0.z + g0[n].w * p0.w +
                   g1[n].x * p1.x + g1[n].y * p1.y + g1[n].z * p1.z + g1[n].w * p1.w;
      h0t[((size_t)(b * 10 + y + 1) * 10 + xx + 1) * 128 + cch] = (bf16)(acc[n][r] + bias);
    }
  }
#undef STAGE_B
#undef LOAD_A
#undef COMPUTE
#undef ITER_I
#undef ITER_N
}

// ---------------- conv-transpose: LDS-staged input patch (+ weights for conv2/3) -------
template <int CIN, int H, int YB, int COUTP, int WM, int NF, int SWM,
          bool WLDS, int INIT, int WIT, bool RELU, bool F32OUT, int SIN_SZ, int SW_SZ>
__global__ __launch_bounds__(256) void convt_kernel(
    const bf16* __restrict__ in, const bf16* __restrict__ wp,
    const float* __restrict__ bias, bf16* __restrict__ out,
    float* __restrict__ fout) {
  constexpr int W = H, WROW = W + 2, ROWB = CIN * 2, GRS = ROWB / 16;
  constexpr int LGR = (GRS == 16) ? 4 : (GRS == 8) ? 3 : 2;
  constexpr int LW = (W == 8) ? 3 : (W == 16) ? 4 : 5;
  constexpr int K = 4 * CIN;
  constexpr int CHUNKS = (YB + 2) * WROW * GRS;
  constexpr int WGR = K / 8;
  __shared__ char sIn[SIN_SZ];
  __shared__ char sW[SW_SZ];

  const int tid = threadIdx.x, wv = tid >> 6, l = tid & 63;
  const int nyb = H / YB;
  const int img = blockIdx.x / nyb, y0 = (blockIdx.x % nyb) * YB;
  const int p = blockIdx.y, py = p >> 1, px = p & 1;

#pragma unroll
  for (int it = 0; it < INIT; ++it) {
    int t = it * 256 + tid;
    int tc = t < CHUNKS ? t : CHUNKS - 1;
    int pix = tc >> LGR, cc = tc & (GRS - 1);
    int ly = pix / WROW, lx = pix % WROW;
    int sb = (cc * 16) ^ ((pix & SWM) << 4);
    gload16(in + ((size_t)((img * (H + 2) + y0 + ly) * (W + 2) + lx)) * CIN + (sb >> 1),
            sIn + it * 4096 + wv * 1024);
  }
  if constexpr (WLDS) {
#pragma unroll
    for (int it = 0; it < WIT; ++it) {
      int t = it * 256 + tid;
      int oc = t / WGR, cc = t % WGR;
      int sb = (cc * 16) ^ ((oc & 7) << 4);
      gload16(wp + (size_t)(p * COUTP + oc) * K + (sb >> 1), sW + it * 4096 + wv * 1024);
    }
  }
  __syncthreads();

  const int lr = l & 15, lkg = l >> 4;
  const int wm = wv & (WM - 1), wn = wv / WM;
  int pcen[2];
#pragma unroll
  for (int m = 0; m < 2; ++m) {
    int r = wm * 32 + m * 16 + lr;
    pcen[m] = ((r >> LW) + 1) * WROW + (r & (W - 1)) + 1;
  }

  f32x4 acc[2][NF] = {};
#pragma unroll 4
  for (int kk = 0; kk < K; kk += 32) {
    const int t4 = kk / CIN;
    const int tyi = t4 >> 1, txi = t4 & 1;
    const int dy = (py == 0) ? (tyi ? -1 : 0) : (tyi ? 0 : 1);
    const int dx = (px == 0) ? (txi ? -1 : 0) : (txi ? 0 : 1);
    const int icb = (kk % CIN) * 2 + lkg * 16;
    bf16x8 av[2], bv[NF];
#pragma unroll
    for (int m = 0; m < 2; ++m) {
      int pixd = pcen[m] + dy * WROW + dx;
      av[m] = *(const bf16x8*)(sIn + pixd * ROWB + (icb ^ ((pixd & SWM) << 4)));
    }
#pragma unroll
    for (int n = 0; n < NF; ++n) {
      int oc = (wn * NF + n) * 16 + lr;
      if constexpr (WLDS) {
        int kb = kk * 2 + lkg * 16;
        bv[n] = *(const bf16x8*)(sW + oc * (K * 2) + (kb ^ ((oc & 7) << 4)));
      } else {
        bv[n] = *(const bf16x8*)(wp + (size_t)(p * COUTP + oc) * K + kk + lkg * 8);
      }
    }
#pragma unroll
    for (int m = 0; m < 2; ++m)
#pragma unroll
      for (int n = 0; n < NF; ++n) acc[m][n] = mfma16(av[m], bv[n], acc[m][n]);
  }

#pragma unroll
  for (int m = 0; m < 2; ++m)
#pragma unroll
    for (int r4 = 0; r4 < 4; ++r4) {
      int r = wm * 32 + m * 16 + lkg * 4 + r4;
      int yy = r >> LW, xx = r & (W - 1);
      int oy = 2 * (y0 + yy) + py, ox = 2 * xx + px;
#pragma unroll
      for (int n = 0; n < NF; ++n) {
        int oc = (wn * NF + n) * 16 + lr;
        float v = acc[m][n][r4];
        if constexpr (F32OUT) {
          if (oc < 3) fout[((size_t)(img * 3 + oc) * (2 * H) + oy) * (2 * H) + ox] = v + bias[oc];
        } else {
          v += bias[oc];
          if constexpr (RELU) v = fmaxf(v, 0.f);
          out[((size_t)(img * (2 * H + 2) + oy + 1) * (2 * H + 2) + ox + 1) * COUTP + oc] = (bf16)v;
        }
      }
    }
}

// ---------------- launch ----------------
extern "C" void kernel_launch(void* const* d_in, const int* in_sizes, int n_in,
                              void* d_out, int out_size, void* d_ws, size_t ws_size,
                              hipStream_t stream) {
  const float* x  = (const float*)d_in[0];
  const float* gw = (const float*)d_in[1];
  const float* gb = (const float*)d_in[2];
  const float* pw = (const float*)d_in[3];
  const float* pb = (const float*)d_in[4];
  const float* w1 = (const float*)d_in[5];
  const float* b1 = (const float*)d_in[6];
  const float* w2 = (const float*)d_in[7];
  const float* b2 = (const float*)d_in[8];
  const float* w3 = (const float*)d_in[9];
  const float* b3 = (const float*)d_in[10];
  float* outp = (float*)d_out;

  char* ws = (char*)d_ws;
  bf16*  xgb  = (bf16*)(ws + 0);          // 1,048,576
  float* gbuf = (float*)(ws + 1048576);   // 8,192
  bf16*  h0t  = (bf16*)(ws + 1056768);    // 6,553,600
  bf16*  w1p  = (bf16*)(ws + 7610368);    // 262,144
  bf16*  h1   = (bf16*)(ws + 7872512);    // 10,616,832
  bf16*  w2p  = (bf16*)(ws + 18489344);   // 65,536
  bf16*  h2   = (bf16*)(ws + 18554880);   // 18,939,904
  bf16*  w3p  = (bf16*)(ws + 37494784);   // 16,384

  border_zero_all<<<1648, 256, 0, stream>>>(h0t, h1, h2);
  gating_kernel<<<256, 256, 0, stream>>>(x, gw, gb, xgb, gbuf);
  convert_w_all<<<672, 256, 0, stream>>>(w1, w1p, w2, w2p, w3, w3p);

  me_gemm_kernel<<<256, 512, 0, stream>>>(pw, xgb, pb, gbuf, h0t);

  convt_kernel<128, 8, 8, 64, 2, 2, 7, false, 7, 0, true, false, 28672, 16>
      <<<dim3(256, 4), 256, 0, stream>>>(h0t, w1p, b1, h1, nullptr);
  convt_kernel<64, 16, 8, 32, 4, 2, 7, true, 6, 4, true, false, 24576, 16384>
      <<<dim3(512, 4), 256, 0, stream>>>(h1, w2p, b2, h2, nullptr);
  convt_kernel<32, 32, 4, 16, 4, 1, 3, true, 4, 1, false, true, 16384, 4096>
      <<<dim3(2048, 4), 256, 0, stream>>>(h2, w3p, b3, nullptr, outp);
}

// Round 6
// 119.150 us; speedup vs baseline: 1.1259x; 1.1259x over previous
//
#include <hip/hip_runtime.h>

typedef __bf16 bf16;
typedef __bf16 bf16x8 __attribute__((ext_vector_type(8)));
typedef float f32x4 __attribute__((ext_vector_type(4)));

__device__ __forceinline__ f32x4 mfma16(bf16x8 a, bf16x8 b, f32x4 c) {
  return __builtin_amdgcn_mfma_f32_16x16x32_bf16(a, b, c, 0, 0, 0);
}

// async global->LDS 16B; LDS dest is wave-uniform base, lane l writes base+l*16.
__device__ __forceinline__ void gload16(const void* g, void* l) {
  __builtin_amdgcn_global_load_lds(
      (const __attribute__((address_space(1))) void*)g,
      (__attribute__((address_space(3))) void*)(uint32_t)(size_t)l, 16, 0, 0);
}

__device__ __forceinline__ bf16x8 cvt8(float4 a, float4 b) {
  bf16x8 r;
  r[0] = (bf16)a.x; r[1] = (bf16)a.y; r[2] = (bf16)a.z; r[3] = (bf16)a.w;
  r[4] = (bf16)b.x; r[5] = (bf16)b.y; r[6] = (bf16)b.z; r[7] = (bf16)b.w;
  return r;
}

// ---------------- gating ----------------
__global__ __launch_bounds__(256) void gating_kernel(
    const float* __restrict__ x, const float* __restrict__ gw,
    const float* __restrict__ gb, bf16* __restrict__ xgb,
    float* __restrict__ gbuf) {
  const int b = blockIdx.x, tid = threadIdx.x;
  __shared__ float xs[256];
  __shared__ float gs[8];
  xs[tid] = x[b * 256 + tid];
  __syncthreads();
  if (tid < 8) {
    float acc = gb[tid];
    for (int i = 0; i < 256; ++i) acc += xs[i] * gw[i * 8 + tid];
    gs[tid] = acc;
  }
  __syncthreads();
  if (tid == 0) {
    float m = gs[0];
    for (int l = 1; l < 8; ++l) m = fmaxf(m, gs[l]);
    float s = 0.f, e[8];
    for (int l = 0; l < 8; ++l) { e[l] = expf(gs[l] - m); s += e[l]; }
    float inv = 1.f / s;
    for (int l = 0; l < 8; ++l) gs[l] = e[l] * inv;
  }
  __syncthreads();
  if (tid < 8) gbuf[b * 8 + tid] = gs[tid];
  bf16* dst = xgb + (size_t)b * 2048;
  for (int k = tid; k < 2048; k += 256)
    dst[k] = (bf16)(xs[k >> 3] * gs[k & 7]);
}

// ---------------- merged weight transform ----------------
template <int CIN, int COUT, int COUTP>
__device__ __forceinline__ void cw_one(const float* __restrict__ w,
                                       bf16* __restrict__ wp, int idx) {
  constexpr int K = 4 * CIN;
  int ic = idx & (CIN - 1);
  int t = (idx / CIN) & 3;
  int oc = (idx / K) % COUTP;
  int p = idx / (K * COUTP);
  bf16 v = (bf16)0.f;
  if (oc < COUT) {
    int py = p >> 1, px = p & 1, tyi = t >> 1, txi = t & 1;
    int ky = py == 0 ? (tyi ? 3 : 1) : (tyi ? 2 : 0);
    int kx = px == 0 ? (txi ? 3 : 1) : (txi ? 2 : 0);
    v = (bf16)w[((ic * COUT + oc) * 4 + ky) * 4 + kx];
  }
  wp[idx] = v;
}

__global__ __launch_bounds__(256) void convert_w_all(
    const float* __restrict__ w1, bf16* __restrict__ w1p,
    const float* __restrict__ w2, bf16* __restrict__ w2p,
    const float* __restrict__ w3, bf16* __restrict__ w3p) {
  int idx = blockIdx.x * 256 + threadIdx.x;
  if (idx < 131072) cw_one<128, 64, 64>(w1, w1p, idx);
  else if (idx < 163840) cw_one<64, 32, 32>(w2, w2p, idx - 131072);
  else if (idx < 172032) cw_one<32, 3, 16>(w3, w3p, idx - 163840);
}

// ---------------- merged halo zero ----------------
template <int HP, int WP, int C>
__device__ __forceinline__ void bz_one(bf16* __restrict__ buf, int idx) {
  constexpr int NCELL = 2 * WP + 2 * (HP - 2);
  constexpr int C8 = C / 8;
  int c8 = idx % C8;
  int rem = idx / C8;
  int cell = rem % NCELL;
  int b = rem / NCELL;
  int y, x;
  if (cell < WP) { y = 0; x = cell; }
  else if (cell < 2 * WP) { y = HP - 1; x = cell - WP; }
  else { int r2 = cell - 2 * WP; y = 1 + (r2 >> 1); x = (r2 & 1) ? WP - 1 : 0; }
  bf16x8 z = {};
  *(bf16x8*)(buf + ((size_t)(b * HP + y) * WP + x) * C + c8 * 8) = z;
}

__global__ __launch_bounds__(256) void border_zero_all(
    bf16* __restrict__ h0t, bf16* __restrict__ h1, bf16* __restrict__ h2) {
  int idx = blockIdx.x * 256 + threadIdx.x;
  if (idx < 147456) bz_one<10, 10, 128>(h0t, idx);
  else if (idx < 286720) bz_one<18, 18, 64>(h1, idx - 147456);
  else if (idx < 421888) bz_one<34, 34, 32>(h2, idx - 286720);
}

// ---------------- fused ME GEMM, 2 blocks/CU ----------------
// C[o,b] = bf16(pw[o,:]) . xgb[b,:] + dot(g[b],pb[o]).
// Grid 512 = 128 M-chunks (BM=64) x 4 N-chunks (BN=64); N-chunk in low bid bits
// so the 4 blocks sharing pw rows run simultaneously (L3 sharing).
// Block 256 thr / 4 waves; wave = 16M x 64N (no A dup). B dbuf in 16KB LDS via
// swizzled-source gload16; A = pw f32 direct + 1-deep reg prefetch; 1 barrier/kt.
__global__ __launch_bounds__(256) void me_gemm_kernel(
    const float* __restrict__ pw, const bf16* __restrict__ xgb,
    const float* __restrict__ pb, const float* __restrict__ gbuf,
    bf16* __restrict__ h0t) {
  __shared__ char sB[16384];  // 2 x 8KB (64 rows x 128B)
  const int tid = threadIdx.x, wv = tid >> 6, l = tid & 63;
  const int lr = l & 15, lkg = l >> 4;
  const int oM0 = (blockIdx.x >> 2) * 64, bN0 = (blockIdx.x & 3) * 64;

  // B staging: chunk tid -> rows 0..31, chunk tid+256 -> rows 32..63
  const int r1 = tid >> 3, c1 = tid & 7;
  const int sb1 = (c1 * 16) ^ ((r1 & 7) << 4);
  const int r2 = r1 + 32;
  const int sb2 = (c1 * 16) ^ ((r2 & 7) << 4);
  const bf16* bsrc1 = xgb + (size_t)(bN0 + r1) * 2048 + (sb1 >> 1);
  const bf16* bsrc2 = xgb + (size_t)(bN0 + r2) * 2048 + (sb2 >> 1);
  const int bdst1 = wv * 1024, bdst2 = 4096 + wv * 1024;

  const float* pAf = pw + (size_t)(oM0 + wv * 16 + lr) * 2048 + lkg * 8;

  int raddrB[4][2];
#pragma unroll
  for (int n = 0; n < 4; ++n) {
    int rb = n * 16 + lr;
#pragma unroll
    for (int ks = 0; ks < 2; ++ks)
      raddrB[n][ks] = rb * 128 + ((ks * 64 + lkg * 16) ^ ((rb & 7) << 4));
  }

  // prologue: stage kt=0, prefetch A(0)
  gload16(bsrc1, sB + bdst1);
  gload16(bsrc2, sB + bdst2);
  float4 c0 = *(const float4*)(pAf);
  float4 c1f = *(const float4*)(pAf + 4);
  float4 c2 = *(const float4*)(pAf + 32);
  float4 c3 = *(const float4*)(pAf + 36);

  f32x4 acc[4] = {};
  __syncthreads();
  for (int kt = 0; kt < 32; ++kt) {
    const int cur = (kt & 1) * 8192;
    float4 n0, n1, n2, n3;
    if (kt < 31) {
      const int nxt = ((kt + 1) & 1) * 8192;
      const int ke = (kt + 1) * 64;
      gload16(bsrc1 + ke, sB + nxt + bdst1);
      gload16(bsrc2 + ke, sB + nxt + bdst2);
      n0 = *(const float4*)(pAf + ke);
      n1 = *(const float4*)(pAf + ke + 4);
      n2 = *(const float4*)(pAf + ke + 32);
      n3 = *(const float4*)(pAf + ke + 36);
    }
    bf16x8 af0 = cvt8(c0, c1f);
    bf16x8 af1 = cvt8(c2, c3);
#pragma unroll
    for (int ks = 0; ks < 2; ++ks)
#pragma unroll
      for (int n = 0; n < 4; ++n) {
        bf16x8 bv = *(const bf16x8*)(sB + cur + raddrB[n][ks]);
        acc[n] = mfma16(ks ? af1 : af0, bv, acc[n]);
      }
    if (kt < 31) { c0 = n0; c1f = n1; c2 = n2; c3 = n3; }
    __syncthreads();
  }

  // epilogue: + dot(g[b], pb[o]) -> h0t padded channels-last
  float4 g0[4], g1[4];
#pragma unroll
  for (int n = 0; n < 4; ++n) {
    int b = bN0 + n * 16 + lr;
    g0[n] = *(const float4*)(gbuf + b * 8);
    g1[n] = *(const float4*)(gbuf + b * 8 + 4);
  }
#pragma unroll
  for (int r = 0; r < 4; ++r) {
    int o = oM0 + wv * 16 + lkg * 4 + r;
    float4 p0 = *(const float4*)(pb + o * 8);
    float4 p1 = *(const float4*)(pb + o * 8 + 4);
    int cch = o >> 6, y = (o >> 3) & 7, xx = o & 7;
#pragma unroll
    for (int n = 0; n < 4; ++n) {
      int b = bN0 + n * 16 + lr;
      float bias = g0[n].x * p0.x + g0[n].y * p0.y + g0[n].z * p0.z + g0[n].w * p0.w +
                   g1[n].x * p1.x + g1[n].y * p1.y + g1[n].z * p1.z + g1[n].w * p1.w;
      h0t[((size_t)(b * 10 + y + 1) * 10 + xx + 1) * 128 + cch] = (bf16)(acc[n][r] + bias);
    }
  }
}

// ---------------- conv-transpose: LDS-staged input patch (+ weights for conv2/3) -------
template <int CIN, int H, int YB, int COUTP, int WM, int NF, int SWM,
          bool WLDS, int INIT, int WIT, bool RELU, bool F32OUT, int SIN_SZ, int SW_SZ>
__global__ __launch_bounds__(256) void convt_kernel(
    const bf16* __restrict__ in, const bf16* __restrict__ wp,
    const float* __restrict__ bias, bf16* __restrict__ out,
    float* __restrict__ fout) {
  constexpr int W = H, WROW = W + 2, ROWB = CIN * 2, GRS = ROWB / 16;
  constexpr int LGR = (GRS == 16) ? 4 : (GRS == 8) ? 3 : 2;
  constexpr int LW = (W == 8) ? 3 : (W == 16) ? 4 : 5;
  constexpr int K = 4 * CIN;
  constexpr int CHUNKS = (YB + 2) * WROW * GRS;
  constexpr int WGR = K / 8;
  __shared__ char sIn[SIN_SZ];
  __shared__ char sW[SW_SZ];

  const int tid = threadIdx.x, wv = tid >> 6, l = tid & 63;
  const int nyb = H / YB;
  const int img = blockIdx.x / nyb, y0 = (blockIdx.x % nyb) * YB;
  const int p = blockIdx.y, py = p >> 1, px = p & 1;

#pragma unroll
  for (int it = 0; it < INIT; ++it) {
    int t = it * 256 + tid;
    int tc = t < CHUNKS ? t : CHUNKS - 1;
    int pix = tc >> LGR, cc = tc & (GRS - 1);
    int ly = pix / WROW, lx = pix % WROW;
    int sb = (cc * 16) ^ ((pix & SWM) << 4);
    gload16(in + ((size_t)((img * (H + 2) + y0 + ly) * (W + 2) + lx)) * CIN + (sb >> 1),
            sIn + it * 4096 + wv * 1024);
  }
  if constexpr (WLDS) {
#pragma unroll
    for (int it = 0; it < WIT; ++it) {
      int t = it * 256 + tid;
      int oc = t / WGR, cc = t % WGR;
      int sb = (cc * 16) ^ ((oc & 7) << 4);
      gload16(wp + (size_t)(p * COUTP + oc) * K + (sb >> 1), sW + it * 4096 + wv * 1024);
    }
  }
  __syncthreads();

  const int lr = l & 15, lkg = l >> 4;
  const int wm = wv & (WM - 1), wn = wv / WM;
  int pcen[2];
#pragma unroll
  for (int m = 0; m < 2; ++m) {
    int r = wm * 32 + m * 16 + lr;
    pcen[m] = ((r >> LW) + 1) * WROW + (r & (W - 1)) + 1;
  }

  f32x4 acc[2][NF] = {};
#pragma unroll 4
  for (int kk = 0; kk < K; kk += 32) {
    const int t4 = kk / CIN;
    const int tyi = t4 >> 1, txi = t4 & 1;
    const int dy = (py == 0) ? (tyi ? -1 : 0) : (tyi ? 0 : 1);
    const int dx = (px == 0) ? (txi ? -1 : 0) : (txi ? 0 : 1);
    const int icb = (kk % CIN) * 2 + lkg * 16;
    bf16x8 av[2], bv[NF];
#pragma unroll
    for (int m = 0; m < 2; ++m) {
      int pixd = pcen[m] + dy * WROW + dx;
      av[m] = *(const bf16x8*)(sIn + pixd * ROWB + (icb ^ ((pixd & SWM) << 4)));
    }
#pragma unroll
    for (int n = 0; n < NF; ++n) {
      int oc = (wn * NF + n) * 16 + lr;
      if constexpr (WLDS) {
        int kb = kk * 2 + lkg * 16;
        bv[n] = *(const bf16x8*)(sW + oc * (K * 2) + (kb ^ ((oc & 7) << 4)));
      } else {
        bv[n] = *(const bf16x8*)(wp + (size_t)(p * COUTP + oc) * K + kk + lkg * 8);
      }
    }
#pragma unroll
    for (int m = 0; m < 2; ++m)
#pragma unroll
      for (int n = 0; n < NF; ++n) acc[m][n] = mfma16(av[m], bv[n], acc[m][n]);
  }

#pragma unroll
  for (int m = 0; m < 2; ++m)
#pragma unroll
    for (int r4 = 0; r4 < 4; ++r4) {
      int r = wm * 32 + m * 16 + lkg * 4 + r4;
      int yy = r >> LW, xx = r & (W - 1);
      int oy = 2 * (y0 + yy) + py, ox = 2 * xx + px;
#pragma unroll
      for (int n = 0; n < NF; ++n) {
        int oc = (wn * NF + n) * 16 + lr;
        float v = acc[m][n][r4];
        if constexpr (F32OUT) {
          if (oc < 3) fout[((size_t)(img * 3 + oc) * (2 * H) + oy) * (2 * H) + ox] = v + bias[oc];
        } else {
          v += bias[oc];
          if constexpr (RELU) v = fmaxf(v, 0.f);
          out[((size_t)(img * (2 * H + 2) + oy + 1) * (2 * H + 2) + ox + 1) * COUTP + oc] = (bf16)v;
        }
      }
    }
}

// ---------------- launch ----------------
extern "C" void kernel_launch(void* const* d_in, const int* in_sizes, int n_in,
                              void* d_out, int out_size, void* d_ws, size_t ws_size,
                              hipStream_t stream) {
  const float* x  = (const float*)d_in[0];
  const float* gw = (const float*)d_in[1];
  const float* gb = (const float*)d_in[2];
  const float* pw = (const float*)d_in[3];
  const float* pb = (const float*)d_in[4];
  const float* w1 = (const float*)d_in[5];
  const float* b1 = (const float*)d_in[6];
  const float* w2 = (const float*)d_in[7];
  const float* b2 = (const float*)d_in[8];
  const float* w3 = (const float*)d_in[9];
  const float* b3 = (const float*)d_in[10];
  float* outp = (float*)d_out;

  char* ws = (char*)d_ws;
  bf16*  xgb  = (bf16*)(ws + 0);          // 1,048,576
  float* gbuf = (float*)(ws + 1048576);   // 8,192
  bf16*  h0t  = (bf16*)(ws + 1056768);    // 6,553,600
  bf16*  w1p  = (bf16*)(ws + 7610368);    // 262,144
  bf16*  h1   = (bf16*)(ws + 7872512);    // 10,616,832
  bf16*  w2p  = (bf16*)(ws + 18489344);   // 65,536
  bf16*  h2   = (bf16*)(ws + 18554880);   // 18,939,904
  bf16*  w3p  = (bf16*)(ws + 37494784);   // 16,384

  border_zero_all<<<1648, 256, 0, stream>>>(h0t, h1, h2);
  gating_kernel<<<256, 256, 0, stream>>>(x, gw, gb, xgb, gbuf);
  convert_w_all<<<672, 256, 0, stream>>>(w1, w1p, w2, w2p, w3, w3p);

  me_gemm_kernel<<<512, 256, 0, stream>>>(pw, xgb, pb, gbuf, h0t);

  convt_kernel<128, 8, 8, 64, 2, 2, 7, false, 7, 0, true, false, 28672, 16>
      <<<dim3(256, 4), 256, 0, stream>>>(h0t, w1p, b1, h1, nullptr);
  convt_kernel<64, 16, 8, 32, 4, 2, 7, true, 6, 4, true, false, 24576, 16384>
      <<<dim3(512, 4), 256, 0, stream>>>(h1, w2p, b2, h2, nullptr);
  convt_kernel<32, 32, 4, 16, 4, 1, 3, true, 4, 1, false, true, 16384, 4096>
      <<<dim3(2048, 4), 256, 0, stream>>>(h2, w3p, b3, nullptr, outp);
}